// Round 18
// baseline (551.833 us; speedup 1.0000x reference)
//
#include <hip/hip_runtime.h>
#include <hip/hip_bf16.h>

#define NN 100000        // nodes per type
#define NE 1000000       // edges per relation
#define FI 128
#define FO 64
#define NB 196           // ceil(NN/512) active buckets
#define CAP 6144         // padded slots per bucket (mean 5120, +14 sigma headroom)
#define RELSTRIDE (256 * CAP)
#define TILE 4096        // edges per csr_place tile
#define PROJ_T 512       // proj blocks per type
#define PLACE_BLOCKS 128 // per relation

typedef unsigned short u16;
typedef unsigned int u32;
typedef __attribute__((ext_vector_type(8))) short short8t;
typedef __attribute__((ext_vector_type(4))) float float4t;

__device__ __forceinline__ float bf2f(u16 u) {
    return __uint_as_float(((u32)u) << 16);
}
__device__ __forceinline__ u16 f2bf(float f) {
    __hip_bfloat16 h = __float2bfloat16(f);
    return *(u16*)&h;
}

// ---------------- init: seed bucket cursors + zero mean_acc ----------------
__global__ __launch_bounds__(256) void init_kernel(int* __restrict__ bcursor,
                                                   float* __restrict__ mean_acc)
{
    const int rel = blockIdx.x;
    const int tid = threadIdx.x;
    bcursor[rel * 256 + tid] = tid * CAP;
    if (tid < 64) mean_acc[rel * 64 + tid] = 0.f;
}

// ---------------- phase1: MFMA proj + al (blocks 0..1023) || csr_place (1024..1535) ----------------
// proj: wave per 16-node tile; C[16x64] = X[16x128] @ W[128x64] via 16 x mfma_16x16x32_bf16.
//   C/D: col(feat within head t) = lane&15, node = n0 + (lane>>4)*4 + reg  [verified r17]
//   al epilogue: head == t; reduce over lo (lanes xor 1,2,4,8) of (acc+bias)*a[t*16+lo].
__global__ __launch_bounds__(256) void phase1_kernel(
    const float* __restrict__ x_p, const float* __restrict__ W_p, const float* __restrict__ b_p,
    const float* __restrict__ p_a0, const float* __restrict__ p_a1,
    const float* __restrict__ p_a2, const float* __restrict__ p_a3,
    const float* __restrict__ x_t, const float* __restrict__ W_t, const float* __restrict__ b_t,
    const float* __restrict__ t_a0, const float* __restrict__ t_a1,
    const float* __restrict__ t_a2, const float* __restrict__ t_a3,
    u16* __restrict__ hb_place, u16* __restrict__ hb_trans,
    float* __restrict__ al_place, float* __restrict__ al_trans,
    const int* __restrict__ ei_pt, const int* __restrict__ ei_tt,
    const int* __restrict__ ei_tp, const int* __restrict__ ei_pp,
    int* __restrict__ bcursor, u32* __restrict__ packed)
{
    __shared__ int smem[512];
    const int bid = blockIdx.x;
    const int tid = threadIdx.x;

    if (bid < 2 * PROJ_T) {
        // ---------------- MFMA projection branch ----------------
        const int ty = (bid >= PROJ_T);
        const float* __restrict__ x = ty ? x_t : x_p;
        const float* __restrict__ W = ty ? W_t : W_p;
        const float* __restrict__ b = ty ? b_t : b_p;
        const float* a0 = ty ? t_a0 : p_a0;
        const float* a1 = ty ? t_a1 : p_a1;
        const float* a2 = ty ? t_a2 : p_a2;
        const float* a3 = ty ? t_a3 : p_a3;
        u16* __restrict__ hout = ty ? hb_trans : hb_place;
        float* __restrict__ al = ty ? al_trans : al_place;

        const int lane = tid & 63;
        const int wv   = tid >> 6;
        const int g    = lane >> 4;      // 0..3
        const int lo   = lane & 15;
        const int wid  = ((bid & (PROJ_T - 1)) << 2) | wv;   // 0..2047 within type

        // stage W fragments (once)
        short8t wf[4][4];
#pragma unroll
        for (int s = 0; s < 4; ++s)
#pragma unroll
            for (int t = 0; t < 4; ++t)
#pragma unroll
                for (int j = 0; j < 8; ++j)
                    wf[s][t][j] = (short)f2bf(W[(s * 32 + g * 8 + j) * FO + t * 16 + lo]);

        float bias[4];
#pragma unroll
        for (int t = 0; t < 4; ++t) bias[t] = b[t * 16 + lo];

        float avv[4][4];   // avv[m][t] = a_m[t*16+lo]
#pragma unroll
        for (int t = 0; t < 4; ++t) {
            avv[0][t] = a0[t * 16 + lo];
            avv[1][t] = a1[t * 16 + lo];
            avv[2][t] = a2[t * 16 + lo];
            avv[3][t] = a3[t * 16 + lo];
        }

        for (int tile = wid; tile < NN / 16; tile += 2048) {
            const int n0 = tile * 16;
            float4t acc[4];
#pragma unroll
            for (int t = 0; t < 4; ++t) { acc[t][0] = 0.f; acc[t][1] = 0.f; acc[t][2] = 0.f; acc[t][3] = 0.f; }

#pragma unroll
            for (int s = 0; s < 4; ++s) {
                const float* __restrict__ xr = x + (size_t)(n0 + lo) * FI + s * 32 + g * 8;
                const float4 u = *(const float4*)xr;
                const float4 v = *(const float4*)(xr + 4);
                short8t af;
                af[0] = (short)f2bf(u.x); af[1] = (short)f2bf(u.y);
                af[2] = (short)f2bf(u.z); af[3] = (short)f2bf(u.w);
                af[4] = (short)f2bf(v.x); af[5] = (short)f2bf(v.y);
                af[6] = (short)f2bf(v.z); af[7] = (short)f2bf(v.w);
#pragma unroll
                for (int t = 0; t < 4; ++t)
                    acc[t] = __builtin_amdgcn_mfma_f32_16x16x32_bf16(af, wf[s][t], acc[t], 0, 0, 0);
            }

            // h store (bias + bf16); node = n0 + g*4 + j, feat = t*16 + lo
#pragma unroll
            for (int t = 0; t < 4; ++t)
#pragma unroll
                for (int j = 0; j < 4; ++j)
                    hout[(size_t)(n0 + g * 4 + j) * FO + t * 16 + lo] = f2bf(acc[t][j] + bias[t]);

            // al epilogue: al[m][node][head=t] = sum_lo (acc+bias)*avv[m][t]
#pragma unroll
            for (int m = 0; m < 4; ++m)
#pragma unroll
                for (int t = 0; t < 4; ++t)
#pragma unroll
                    for (int j = 0; j < 4; ++j) {
                        float p = (acc[t][j] + bias[t]) * avv[m][t];
                        p += __shfl_xor(p, 1);
                        p += __shfl_xor(p, 2);
                        p += __shfl_xor(p, 4);
                        p += __shfl_xor(p, 8);
                        if (lo == 0)
                            al[(size_t)m * NN * 4 + (size_t)(n0 + g * 4 + j) * 4 + t] = p;
                    }
        }
    } else {
        // ---------------- csr_place branch ----------------
        const int pb = bid - 2 * PROJ_T;
        const int rel = pb >> 7;
        const int bx  = pb & 127;
        const int* ei = (rel == 0) ? ei_pt : (rel == 1) ? ei_tt : (rel == 2) ? ei_tp : ei_pp;
        u32* pk = packed + (size_t)rel * RELSTRIDE;

        int* lh = smem;
        int* lb = smem + 256;

        const int ntiles = (NE + TILE - 1) / TILE;
        for (int tile = bx; tile < ntiles; tile += PLACE_BLOCKS) {
            const int t0 = tile * TILE;
            lh[tid] = 0;
            __syncthreads();

            int d[TILE / 256];
#pragma unroll
            for (int i = 0; i < TILE / 256; ++i) {
                const int idx = t0 + i * 256 + tid;
                d[i] = (idx < NE) ? ei[NE + idx] : -1;
                if (d[i] >= 0) atomicAdd(&lh[d[i] >> 9], 1);
            }
            __syncthreads();
            if (lh[tid]) lb[tid] = atomicAdd(&bcursor[rel * 256 + tid], lh[tid]);
            __syncthreads();
#pragma unroll
            for (int i = 0; i < TILE / 256; ++i) {
                const int idx = t0 + i * 256 + tid;
                if (d[i] >= 0) {
                    const int src = ei[idx];
                    const int slot = atomicAdd(&lb[d[i] >> 9], 1);
                    pk[slot] = ((u32)(d[i] & 511) << 17) | (u32)src;
                }
            }
            __syncthreads();
        }
    }
}

// ---------------- CSR 2: per-bucket sort -> ofp + perm + precomputed edge weights (bf16x4) ----------------
__global__ __launch_bounds__(256) void csr_build(
    const u32* __restrict__ packed, const int* __restrict__ bcursor,
    int2* __restrict__ ofp, int* __restrict__ perm, ushort4* __restrict__ pal,
    const float* __restrict__ al_place, const float* __restrict__ al_trans)
{
    const int rel = blockIdx.y;
    const int b = blockIdx.x;                 // 0..NB-1
    const int tid = threadIdx.x;
    const int base = b * CAP;
    const int cnt  = bcursor[rel * 256 + b] - base;
    const u32* pk = packed + (size_t)rel * RELSTRIDE + base;
    int2* of = ofp + (size_t)rel * NN;
    int* pm = perm + (size_t)rel * RELSTRIDE;
    ushort4* pw = pal + (size_t)rel * RELSTRIDE;

    const float* als; const float* ald;
    if (rel == 0)      { als = al_place + 0 * NN * 4; ald = al_trans + 2 * NN * 4; }
    else if (rel == 1) { als = al_trans + 1 * NN * 4; ald = al_trans + 3 * NN * 4; }
    else if (rel == 2) { als = al_trans + 0 * NN * 4; ald = al_place + 2 * NN * 4; }
    else               { als = al_place + 1 * NN * 4; ald = al_place + 3 * NN * 4; }

    __shared__ int h[512];
    __shared__ int cur[512];
    h[tid] = 0; h[tid + 256] = 0;
    __syncthreads();
    for (int i = tid; i < cnt; i += 256)
        atomicAdd(&h[pk[i] >> 17], 1);
    __syncthreads();
    const int o0 = h[tid], o1 = h[tid + 256];
    for (int off = 1; off < 512; off <<= 1) {
        const int a0 = (tid >= off) ? h[tid - off] : 0;
        const int a1 = (tid + 256 >= off) ? h[tid + 256 - off] : 0;
        __syncthreads();
        h[tid] += a0; h[tid + 256] += a1;
        __syncthreads();
    }
    const int e0 = base + h[tid] - o0;
    const int e1 = base + h[tid + 256] - o1;
    const int gd0 = b * 512 + tid;
    const int gd1 = gd0 + 256;
    if (gd0 < NN) of[gd0] = make_int2(e0, e0 + o0);
    if (gd1 < NN) of[gd1] = make_int2(e1, e1 + o1);
    cur[tid] = e0; cur[tid + 256] = e1;
    __syncthreads();
    for (int i = tid; i < cnt; i += 256) {
        const u32 e = pk[i];
        const int src = (int)(e & 0x1FFFFu);
        const int dl  = (int)(e >> 17);
        const int slot = atomicAdd(&cur[dl], 1);
        const int gd = b * 512 + dl;
        const float4 va = *(const float4*)(als + (size_t)src * 4);
        const float4 vd = *(const float4*)(ald + (size_t)gd * 4);
        float a0 = va.x + vd.x; a0 = a0 > 0.f ? a0 : 0.2f * a0;
        float a1 = va.y + vd.y; a1 = a1 > 0.f ? a1 : 0.2f * a1;
        float a2 = va.z + vd.z; a2 = a2 > 0.f ? a2 : 0.2f * a2;
        float a3 = va.w + vd.w; a3 = a3 > 0.f ? a3 : 0.2f * a3;
        ushort4 w;
        w.x = f2bf(__expf(a0));
        w.y = f2bf(__expf(a1));
        w.z = f2bf(__expf(a2));
        w.w = f2bf(__expf(a3));
        pm[slot] = src;
        pw[slot] = w;
    }
}

// ---------------- accumulate: wave per dst node, 2 nodes in flight; streaming weights ----------------
#define EDGE4(pm_, pw_, hb_, cc, num_, den_, head_, lane_)                                          \
    {                                                                                               \
        const int s0 = pm_[cc], s1 = pm_[cc + 1], s2 = pm_[cc + 2], s3 = pm_[cc + 3];               \
        const ushort4 q0 = pw_[cc], q1 = pw_[cc + 1], q2 = pw_[cc + 2], q3 = pw_[cc + 3];           \
        const float e0 = bf2f((head_ == 0) ? q0.x : (head_ == 1) ? q0.y : (head_ == 2) ? q0.z : q0.w);\
        const float e1 = bf2f((head_ == 0) ? q1.x : (head_ == 1) ? q1.y : (head_ == 2) ? q1.z : q1.w);\
        const float e2 = bf2f((head_ == 0) ? q2.x : (head_ == 1) ? q2.y : (head_ == 2) ? q2.z : q2.w);\
        const float e3 = bf2f((head_ == 0) ? q3.x : (head_ == 1) ? q3.y : (head_ == 2) ? q3.z : q3.w);\
        const float h0 = bf2f(hb_[(size_t)s0 * FO + lane_]);                                        \
        const float h1 = bf2f(hb_[(size_t)s1 * FO + lane_]);                                        \
        const float h2 = bf2f(hb_[(size_t)s2 * FO + lane_]);                                        \
        const float h3 = bf2f(hb_[(size_t)s3 * FO + lane_]);                                        \
        num_ = fmaf(h0, e0, num_);                                                                  \
        num_ = fmaf(h1, e1, num_);                                                                  \
        num_ = fmaf(h2, e2, num_);                                                                  \
        num_ = fmaf(h3, e3, num_);                                                                  \
        den_ += (e0 + e1) + (e2 + e3);                                                              \
    }

#define EDGE1(pm_, pw_, hb_, cc, num_, den_, head_, lane_)                                          \
    {                                                                                               \
        const int s0 = pm_[cc];                                                                     \
        const ushort4 q0 = pw_[cc];                                                                 \
        const float e0 = bf2f((head_ == 0) ? q0.x : (head_ == 1) ? q0.y : (head_ == 2) ? q0.z : q0.w);\
        const float h0 = bf2f(hb_[(size_t)s0 * FO + lane_]);                                        \
        num_ = fmaf(h0, e0, num_);                                                                  \
        den_ += e0;                                                                                 \
    }

__global__ __launch_bounds__(256) void acc_kernel(
    const u16* __restrict__ hb_place, const u16* __restrict__ hb_trans,
    const int2* __restrict__ ofp, const int* __restrict__ perm,
    const ushort4* __restrict__ pal, u16* __restrict__ outb)
{
    const int rel = blockIdx.y;
    const u16* hb = (rel == 0 || rel == 3) ? hb_place : hb_trans;
    const int2* of = ofp + (size_t)rel * NN;
    const int* pm = perm + (size_t)rel * RELSTRIDE;
    const ushort4* pw = pal + (size_t)rel * RELSTRIDE;
    u16* ob = outb + (size_t)rel * NN * FO;

    const int lane = threadIdx.x & 63;
    const int wid  = threadIdx.x >> 6;
    const int head = lane >> 4;

    const int gw = blockIdx.x * 4 + wid;
    const int nw = gridDim.x * 4;
    for (int n = gw; n < NN; n += 2 * nw) {
        const int n2 = n + nw;
        const int nu = __builtin_amdgcn_readfirstlane(n);
        const int2 be = of[nu];
        int c1 = be.x;
        const int end1 = be.y;
        float num1 = 0.f, den1 = 0.f;

        if (n2 < NN) {
            const int nu2 = __builtin_amdgcn_readfirstlane(n2);
            const int2 be2 = of[nu2];
            int c2 = be2.x;
            const int end2 = be2.y;
            float num2 = 0.f, den2 = 0.f;

            while (c1 + 4 <= end1 && c2 + 4 <= end2) {
                EDGE4(pm, pw, hb, c1, num1, den1, head, lane);
                EDGE4(pm, pw, hb, c2, num2, den2, head, lane);
                c1 += 4; c2 += 4;
            }
            for (; c1 + 4 <= end1; c1 += 4) EDGE4(pm, pw, hb, c1, num1, den1, head, lane);
            for (; c1 < end1; ++c1)         EDGE1(pm, pw, hb, c1, num1, den1, head, lane);
            for (; c2 + 4 <= end2; c2 += 4) EDGE4(pm, pw, hb, c2, num2, den2, head, lane);
            for (; c2 < end2; ++c2)         EDGE1(pm, pw, hb, c2, num2, den2, head, lane);

            const float outv1 = fmaxf(num1 / (den1 + 1e-16f), 0.f);
            const float outv2 = fmaxf(num2 / (den2 + 1e-16f), 0.f);
            ob[(size_t)nu * FO + lane]  = f2bf(outv1);
            ob[(size_t)nu2 * FO + lane] = f2bf(outv2);
        } else {
            for (; c1 + 4 <= end1; c1 += 4) EDGE4(pm, pw, hb, c1, num1, den1, head, lane);
            for (; c1 < end1; ++c1)         EDGE1(pm, pw, hb, c1, num1, den1, head, lane);
            const float outv1 = fmaxf(num1 / (den1 + 1e-16f), 0.f);
            ob[(size_t)nu * FO + lane] = f2bf(outv1);
        }
    }
}

// ---------------- semantic: ts[f] += tanh(out_row @ kW + kb)[f]; 4-row chains ----------------
__global__ __launch_bounds__(256) void sem_kernel(
    const u16* __restrict__ outb, const float* __restrict__ kW, const float* __restrict__ kb,
    float* __restrict__ mean_acc)
{
    const int rel = blockIdx.y;
    const u16* ob = outb + (size_t)rel * NN * FO;
    const int QN = NN / 4;

    const int lane = threadIdx.x & 63;
    const int wid  = threadIdx.x >> 6;

    float kwc[FO];
#pragma unroll
    for (int k = 0; k < FO; ++k) kwc[k] = kW[k * FO + lane];
    const float kbv = kb[lane];

    float ts = 0.f;
    const int gw = blockIdx.x * 4 + wid;
    const int nw = gridDim.x * 4;
    for (int n = gw; n < QN; n += nw) {
        const int r0 = __builtin_amdgcn_readfirstlane(n);
        const int r1 = r0 + QN;
        const int r2 = r0 + 2 * QN;
        const int r3 = r0 + 3 * QN;
        const u32* w0 = (const u32*)(ob + (size_t)r0 * FO);
        const u32* w1 = (const u32*)(ob + (size_t)r1 * FO);
        const u32* w2 = (const u32*)(ob + (size_t)r2 * FO);
        const u32* w3 = (const u32*)(ob + (size_t)r3 * FO);
        float y0 = kbv, y1 = kbv, y2 = kbv, y3 = kbv;
#pragma unroll
        for (int i = 0; i < 32; ++i) {
            const u32 a = w0[i], b = w1[i], c = w2[i], d = w3[i];
            y0 = fmaf(__uint_as_float(a << 16),         kwc[2 * i],     y0);
            y0 = fmaf(__uint_as_float(a & 0xffff0000u), kwc[2 * i + 1], y0);
            y1 = fmaf(__uint_as_float(b << 16),         kwc[2 * i],     y1);
            y1 = fmaf(__uint_as_float(b & 0xffff0000u), kwc[2 * i + 1], y1);
            y2 = fmaf(__uint_as_float(c << 16),         kwc[2 * i],     y2);
            y2 = fmaf(__uint_as_float(c & 0xffff0000u), kwc[2 * i + 1], y2);
            y3 = fmaf(__uint_as_float(d << 16),         kwc[2 * i],     y3);
            y3 = fmaf(__uint_as_float(d & 0xffff0000u), kwc[2 * i + 1], y3);
        }
        ts += (tanhf(y0) + tanhf(y1)) + (tanhf(y2) + tanhf(y3));
    }

    __shared__ float red[4][64];
    red[wid][lane] = ts;
    __syncthreads();
    if (wid == 0) {
        const float sum = red[0][lane] + red[1][lane] + red[2][lane] + red[3][lane];
        unsafeAtomicAdd(&mean_acc[rel * 64 + lane], sum);
    }
}

// ---------------- combine: attn computed inline; out = a0*out_r0 + a1*out_r1 (f32 out) ----------------
__global__ __launch_bounds__(256) void combine_kernel(
    const u16* __restrict__ outb, const float* __restrict__ mean_acc,
    const float* __restrict__ q, float* __restrict__ out)
{
    const int lane = threadIdx.x & 63;
    const int type = blockIdx.y;           // 0 = place (rels 2,3), 1 = trans (rels 0,1)
    const int r0i = (type == 0) ? 2 : 0;

    const float qv = q[lane];
    float s0 = qv * mean_acc[r0i * 64 + lane] * (1.0f / (float)NN);
    float s1 = qv * mean_acc[(r0i + 1) * 64 + lane] * (1.0f / (float)NN);
#pragma unroll
    for (int off = 1; off < 64; off <<= 1) {
        s0 += __shfl_xor(s0, off);
        s1 += __shfl_xor(s1, off);
    }
    const float m = fmaxf(s0, s1);
    const float e0 = expf(s0 - m), e1 = expf(s1 - m);
    const float a0 = e0 / (e0 + e1);
    const float a1 = e1 / (e0 + e1);

    const ushort4* o0 = (const ushort4*)(outb + (size_t)r0i * NN * FO);
    const ushort4* o1 = (const ushort4*)(outb + (size_t)(r0i + 1) * NN * FO);
    float4* dst = (float4*)(out + (size_t)type * NN * FO);
    const int n4 = NN * FO / 4;
    const int stride = gridDim.x * 256;
    for (int i = blockIdx.x * 256 + threadIdx.x; i < n4; i += stride) {
        const ushort4 u = o0[i];
        const ushort4 w = o1[i];
        float4 r;
        r.x = a0 * bf2f(u.x) + a1 * bf2f(w.x);
        r.y = a0 * bf2f(u.y) + a1 * bf2f(w.y);
        r.z = a0 * bf2f(u.z) + a1 * bf2f(w.z);
        r.w = a0 * bf2f(u.w) + a1 * bf2f(w.w);
        dst[i] = r;
    }
}

extern "C" void kernel_launch(void* const* d_in, const int* in_sizes, int n_in,
                              void* d_out, int out_size, void* d_ws, size_t ws_size,
                              hipStream_t stream)
{
    const float* x_place = (const float*)d_in[0];
    const float* x_trans = (const float*)d_in[1];
    const float* W_place = (const float*)d_in[2];
    const float* b_place = (const float*)d_in[3];
    const float* W_trans = (const float*)d_in[4];
    const float* b_trans = (const float*)d_in[5];
    const float* as_pt = (const float*)d_in[6];
    const float* ad_pt = (const float*)d_in[7];
    const float* as_tp = (const float*)d_in[8];
    const float* ad_tp = (const float*)d_in[9];
    const float* as_pp = (const float*)d_in[10];
    const float* ad_pp = (const float*)d_in[11];
    const float* as_tt = (const float*)d_in[12];
    const float* ad_tt = (const float*)d_in[13];
    const float* q  = (const float*)d_in[14];
    const float* kW = (const float*)d_in[15];
    const float* kb = (const float*)d_in[16];
    const int* ei_pt = (const int*)d_in[17];
    const int* ei_tp = (const int*)d_in[18];
    const int* ei_pp = (const int*)d_in[19];
    const int* ei_tt = (const int*)d_in[20];

    // ---- workspace layout (~194 MB) ----
    char* ws = (char*)d_ws;
    u16* hb_place = (u16*)ws;                                     // 12.8 MB
    u16* hb_trans = hb_place + (size_t)NN * FO;                   // 12.8 MB
    float* al_place = (float*)(hb_trans + (size_t)NN * FO);       // 6.4 MB
    float* al_trans = al_place + 4 * (size_t)NN * 4;              // 6.4 MB
    u16* outb = (u16*)(al_trans + 4 * (size_t)NN * 4);            // 51.2 MB
    int2* ofp = (int2*)(outb + 4 * (size_t)NN * FO);              // 3.2 MB
    int* perm = (int*)(ofp + 4 * (size_t)NN);                     // 25.2 MB
    u32* packed = (u32*)(perm + 4 * (size_t)RELSTRIDE);           // 25.2 MB
    ushort4* pal = (ushort4*)(packed + 4 * (size_t)RELSTRIDE);    // 50.3 MB
    int* bcursor = (int*)(pal + 4 * (size_t)RELSTRIDE);           // 4 KB
    float* mean_acc = (float*)(bcursor + 4 * 256);                // 1 KB

    init_kernel<<<4, 256, 0, stream>>>(bcursor, mean_acc);

    phase1_kernel<<<2 * PROJ_T + 4 * PLACE_BLOCKS, 256, 0, stream>>>(
        x_place, W_place, b_place, as_pt, as_pp, ad_tp, ad_pp,
        x_trans, W_trans, b_trans, as_tp, as_tt, ad_pt, ad_tt,
        hb_place, hb_trans, al_place, al_trans,
        ei_pt, ei_tt, ei_tp, ei_pp, bcursor, packed);

    csr_build<<<dim3(NB, 4), 256, 0, stream>>>(packed, bcursor, ofp, perm, pal,
                                               al_place, al_trans);

    acc_kernel<<<dim3(1024, 4), 256, 0, stream>>>(hb_place, hb_trans, ofp, perm, pal, outb);

    sem_kernel<<<dim3(512, 4), 256, 0, stream>>>(outb, kW, kb, mean_acc);

    combine_kernel<<<dim3(1024, 2), 256, 0, stream>>>(outb, mean_acc, q, (float*)d_out);
}

// Round 19
// 462.404 us; speedup vs baseline: 1.1934x; 1.1934x over previous
//
#include <hip/hip_runtime.h>
#include <hip/hip_bf16.h>

#define NN 100000        // nodes per type
#define NE 1000000       // edges per relation
#define FI 128
#define FO 64
#define NB 196           // ceil(NN/512) active buckets
#define CAP 8192         // padded slots per bucket (mean 5120, 42 sigma headroom)
#define RELSTRIDE (256 * CAP)
#define TILE 4096        // edges per csr_place tile
#define PROJ_T 512       // proj blocks per type
#define PLACE_BLOCKS 128 // per relation
#define ALB 128          // al blocks per (type,part) group

typedef unsigned short u16;
typedef unsigned int u32;
typedef __attribute__((ext_vector_type(8))) short short8t;
typedef __attribute__((ext_vector_type(4))) float float4t;

__device__ __forceinline__ float bf2f(u16 u) {
    return __uint_as_float(((u32)u) << 16);
}
__device__ __forceinline__ u16 f2bf(float f) {
    __hip_bfloat16 h = __float2bfloat16(f);
    return *(u16*)&h;
}

// ---------------- init: seed bucket cursors + zero mean_acc ----------------
__global__ __launch_bounds__(256) void init_kernel(int* __restrict__ bcursor,
                                                   float* __restrict__ mean_acc)
{
    const int rel = blockIdx.x;
    const int tid = threadIdx.x;
    bcursor[rel * 256 + tid] = tid * CAP;
    if (tid < 64) mean_acc[rel * 64 + tid] = 0.f;
}

// ---------------- phase1: MFMA proj (blocks 0..1023) || csr_place (blocks 1024..1535) ----------------
// proj: wave per 16-node tile; C[16x64] = X[16x128] @ W[128x64] via 16 x mfma_16x16x32_bf16.
//   A-frag: row = lane&15, k = s*32 + (lane>>4)*8 + j
//   B-frag: col = lane&15, k = s*32 + (lane>>4)*8 + j  (W staged to 16 frags in VGPRs, once)
//   C/D:    col = lane&15, row(node) = (lane>>4)*4 + reg   [verified r17]
// place: packed entry (dst&511)<<17 | src ; bucket b base = b*CAP.
__global__ __launch_bounds__(256) void phase1_kernel(
    const float* __restrict__ x_p, const float* __restrict__ W_p, const float* __restrict__ b_p,
    const float* __restrict__ x_t, const float* __restrict__ W_t, const float* __restrict__ b_t,
    u16* __restrict__ hb_place, u16* __restrict__ hb_trans,
    const int* __restrict__ ei_pt, const int* __restrict__ ei_tt,
    const int* __restrict__ ei_tp, const int* __restrict__ ei_pp,
    int* __restrict__ bcursor, u32* __restrict__ packed)
{
    __shared__ int smem[512];
    const int bid = blockIdx.x;
    const int tid = threadIdx.x;

    if (bid < 2 * PROJ_T) {
        // ---------------- MFMA projection branch ----------------
        const int ty = (bid >= PROJ_T);
        const float* __restrict__ x = ty ? x_t : x_p;
        const float* __restrict__ W = ty ? W_t : W_p;
        const float* __restrict__ b = ty ? b_t : b_p;
        u16* __restrict__ hout = ty ? hb_trans : hb_place;

        const int lane = tid & 63;
        const int wv   = tid >> 6;
        const int g    = lane >> 4;      // 0..3
        const int lo   = lane & 15;      // A-row / C-col / B-col
        const int wid  = ((bid & (PROJ_T - 1)) << 2) | wv;   // 0..2047 within type

        // stage W fragments (once): wf[s][t] = W[k=s*32+g*8+j][t*16+lo], bf16
        short8t wf[4][4];
#pragma unroll
        for (int s = 0; s < 4; ++s)
#pragma unroll
            for (int t = 0; t < 4; ++t)
#pragma unroll
                for (int j = 0; j < 8; ++j)
                    wf[s][t][j] = (short)f2bf(W[(s * 32 + g * 8 + j) * FO + t * 16 + lo]);

        float bias[4];
#pragma unroll
        for (int t = 0; t < 4; ++t) bias[t] = b[t * 16 + lo];

        for (int tile = wid; tile < NN / 16; tile += 2048) {
            const int n0 = tile * 16;
            float4t acc[4];
#pragma unroll
            for (int t = 0; t < 4; ++t) { acc[t][0] = 0.f; acc[t][1] = 0.f; acc[t][2] = 0.f; acc[t][3] = 0.f; }

#pragma unroll
            for (int s = 0; s < 4; ++s) {
                const float* __restrict__ xr = x + (size_t)(n0 + lo) * FI + s * 32 + g * 8;
                const float4 u = *(const float4*)xr;
                const float4 v = *(const float4*)(xr + 4);
                short8t af;
                af[0] = (short)f2bf(u.x); af[1] = (short)f2bf(u.y);
                af[2] = (short)f2bf(u.z); af[3] = (short)f2bf(u.w);
                af[4] = (short)f2bf(v.x); af[5] = (short)f2bf(v.y);
                af[6] = (short)f2bf(v.z); af[7] = (short)f2bf(v.w);
#pragma unroll
                for (int t = 0; t < 4; ++t)
                    acc[t] = __builtin_amdgcn_mfma_f32_16x16x32_bf16(af, wf[s][t], acc[t], 0, 0, 0);
            }

            // epilogue: bias + bf16 store. node = n0 + g*4 + j, feat = t*16 + lo
#pragma unroll
            for (int t = 0; t < 4; ++t)
#pragma unroll
                for (int j = 0; j < 4; ++j)
                    hout[(size_t)(n0 + g * 4 + j) * FO + t * 16 + lo] = f2bf(acc[t][j] + bias[t]);
        }
    } else {
        // ---------------- csr_place branch ----------------
        const int pb = bid - 2 * PROJ_T;
        const int rel = pb >> 7;            // /128
        const int bx  = pb & 127;
        const int* ei = (rel == 0) ? ei_pt : (rel == 1) ? ei_tt : (rel == 2) ? ei_tp : ei_pp;
        u32* pk = packed + (size_t)rel * RELSTRIDE;

        int* lh = smem;         // per-tile bucket hist
        int* lb = smem + 256;   // per-tile bucket cursor

        const int ntiles = (NE + TILE - 1) / TILE;
        for (int tile = bx; tile < ntiles; tile += PLACE_BLOCKS) {
            const int t0 = tile * TILE;
            lh[tid] = 0;
            __syncthreads();

            int d[TILE / 256];
#pragma unroll
            for (int i = 0; i < TILE / 256; ++i) {
                const int idx = t0 + i * 256 + tid;
                d[i] = (idx < NE) ? ei[NE + idx] : -1;
                if (d[i] >= 0) atomicAdd(&lh[d[i] >> 9], 1);
            }
            __syncthreads();
            if (lh[tid]) lb[tid] = atomicAdd(&bcursor[rel * 256 + tid], lh[tid]);
            __syncthreads();
#pragma unroll
            for (int i = 0; i < TILE / 256; ++i) {
                const int idx = t0 + i * 256 + tid;
                if (d[i] >= 0) {
                    const int src = ei[idx];
                    const int slot = atomicAdd(&lb[d[i] >> 9], 1);
                    pk[slot] = ((u32)(d[i] & 511) << 17) | (u32)src;
                }
            }
            __syncthreads();
        }
    }
}

// ---------------- CSR 2 + al: per-bucket fine sort (bx < NB)  ||  attention logits (bx >= NB) ----------------
// al branch: type = by>>1, part = by&1; al_m[n][head] = sum_d h[n][head*16+d] * a_m[head*16+d]
__global__ __launch_bounds__(256) void csr_build_al(
    const u32* __restrict__ packed, const int* __restrict__ bcursor,
    int2* __restrict__ ofp, int* __restrict__ perm,
    const u16* __restrict__ hb_place, const u16* __restrict__ hb_trans,
    const float* __restrict__ as_pt, const float* __restrict__ as_pp,
    const float* __restrict__ ad_tp, const float* __restrict__ ad_pp,
    const float* __restrict__ as_tp, const float* __restrict__ as_tt,
    const float* __restrict__ ad_pt, const float* __restrict__ ad_tt,
    float* __restrict__ al_place, float* __restrict__ al_trans)
{
    const int by = blockIdx.y;
    const int bx = blockIdx.x;
    const int tid = threadIdx.x;

    if (bx < NB) {
        const int rel = by;
        const int b = bx;
        const int base = b * CAP;
        const int cnt  = bcursor[rel * 256 + b] - base;
        const u32* pk = packed + (size_t)rel * RELSTRIDE + base;
        int2* of = ofp + (size_t)rel * NN;
        int* pm = perm + (size_t)rel * RELSTRIDE;

        __shared__ int h[512];
        __shared__ int cur[512];
        h[tid] = 0; h[tid + 256] = 0;
        __syncthreads();
        for (int i = tid; i < cnt; i += 256)
            atomicAdd(&h[pk[i] >> 17], 1);
        __syncthreads();
        const int o0 = h[tid], o1 = h[tid + 256];
        for (int off = 1; off < 512; off <<= 1) {
            const int a0 = (tid >= off) ? h[tid - off] : 0;
            const int a1 = (tid + 256 >= off) ? h[tid + 256 - off] : 0;
            __syncthreads();
            h[tid] += a0; h[tid + 256] += a1;
            __syncthreads();
        }
        const int e0 = base + h[tid] - o0;
        const int e1 = base + h[tid + 256] - o1;
        const int gd0 = b * 512 + tid;
        const int gd1 = gd0 + 256;
        if (gd0 < NN) of[gd0] = make_int2(e0, e0 + o0);
        if (gd1 < NN) of[gd1] = make_int2(e1, e1 + o1);
        cur[tid] = e0; cur[tid + 256] = e1;
        __syncthreads();
        for (int i = tid; i < cnt; i += 256) {
            const u32 e = pk[i];
            const int slot = atomicAdd(&cur[e >> 17], 1);
            pm[slot] = (int)(e & 0x1FFFFu);
        }
    } else {
        // ---------------- al branch ----------------
        const int ab = bx - NB;           // 0..ALB-1
        const int type = by >> 1;
        const int part = by & 1;
        const u16* hb = type ? hb_trans : hb_place;
        float* al = type ? al_trans : al_place;
        const float* a0 = type ? as_tp : as_pt;
        const float* a1 = type ? as_tt : as_pp;
        const float* a2 = type ? ad_pt : ad_tp;
        const float* a3 = type ? ad_tt : ad_pp;

        const int lane = tid & 63;
        const int wv   = tid >> 6;
        const int head = lane >> 4;
        const float av0 = a0[lane];
        const float av1 = a1[lane];
        const float av2 = a2[lane];
        const float av3 = a3[lane];

        const int HN = NN / 2;            // 50000
        const int nw = ALB * 4;           // 512 waves per (type,part)
        for (int n = part * HN + ab * 4 + wv; n < (part + 1) * HN; n += nw) {
            const float hv = bf2f(hb[(size_t)n * FO + lane]);
            float p0 = hv * av0, p1 = hv * av1, p2 = hv * av2, p3 = hv * av3;
#pragma unroll
            for (int off = 1; off < 16; off <<= 1) {
                p0 += __shfl_xor(p0, off);
                p1 += __shfl_xor(p1, off);
                p2 += __shfl_xor(p2, off);
                p3 += __shfl_xor(p3, off);
            }
            if ((lane & 15) == 0) {
                al[0 * NN * 4 + n * 4 + head] = p0;
                al[1 * NN * 4 + n * 4 + head] = p1;
                al[2 * NN * 4 + n * 4 + head] = p2;
                al[3 * NN * 4 + n * 4 + head] = p3;
            }
        }
    }
}

// ---------------- accumulate: wave per dst node, 2 nodes in flight ----------------
// rel 0: pt -> trans r0 ; rel 1: tt -> trans r1 ; rel 2: tp -> place r0 ; rel 3: pp -> place r1
#define EDGE4(pm_, als_, hb_, cc, advh_, num_, den_, head_, lane_)                                  \
    {                                                                                               \
        const int s0 = pm_[cc], s1 = pm_[cc + 1], s2 = pm_[cc + 2], s3 = pm_[cc + 3];               \
        const float4 v0 = *(const float4*)(als_ + (size_t)s0 * 4);                                  \
        const float4 v1 = *(const float4*)(als_ + (size_t)s1 * 4);                                  \
        const float4 v2 = *(const float4*)(als_ + (size_t)s2 * 4);                                  \
        const float4 v3 = *(const float4*)(als_ + (size_t)s3 * 4);                                  \
        float a0 = ((head_ == 0) ? v0.x : (head_ == 1) ? v0.y : (head_ == 2) ? v0.z : v0.w) + advh_;\
        float a1 = ((head_ == 0) ? v1.x : (head_ == 1) ? v1.y : (head_ == 2) ? v1.z : v1.w) + advh_;\
        float a2 = ((head_ == 0) ? v2.x : (head_ == 1) ? v2.y : (head_ == 2) ? v2.z : v2.w) + advh_;\
        float a3 = ((head_ == 0) ? v3.x : (head_ == 1) ? v3.y : (head_ == 2) ? v3.z : v3.w) + advh_;\
        a0 = a0 > 0.f ? a0 : 0.2f * a0;                                                             \
        a1 = a1 > 0.f ? a1 : 0.2f * a1;                                                             \
        a2 = a2 > 0.f ? a2 : 0.2f * a2;                                                             \
        a3 = a3 > 0.f ? a3 : 0.2f * a3;                                                             \
        const float e0 = __expf(a0), e1 = __expf(a1), e2 = __expf(a2), e3 = __expf(a3);             \
        const float h0 = bf2f(hb_[(size_t)s0 * FO + lane_]);                                        \
        const float h1 = bf2f(hb_[(size_t)s1 * FO + lane_]);                                        \
        const float h2 = bf2f(hb_[(size_t)s2 * FO + lane_]);                                        \
        const float h3 = bf2f(hb_[(size_t)s3 * FO + lane_]);                                        \
        num_ = fmaf(h0, e0, num_);                                                                  \
        num_ = fmaf(h1, e1, num_);                                                                  \
        num_ = fmaf(h2, e2, num_);                                                                  \
        num_ = fmaf(h3, e3, num_);                                                                  \
        den_ += (e0 + e1) + (e2 + e3);                                                              \
    }

#define EDGE1(pm_, als_, hb_, cc, advh_, num_, den_, head_, lane_)                                  \
    {                                                                                               \
        const int s0 = pm_[cc];                                                                     \
        const float4 v0 = *(const float4*)(als_ + (size_t)s0 * 4);                                  \
        float a0 = ((head_ == 0) ? v0.x : (head_ == 1) ? v0.y : (head_ == 2) ? v0.z : v0.w) + advh_;\
        a0 = a0 > 0.f ? a0 : 0.2f * a0;                                                             \
        const float e0 = __expf(a0);                                                                \
        const float h0 = bf2f(hb_[(size_t)s0 * FO + lane_]);                                        \
        num_ = fmaf(h0, e0, num_);                                                                  \
        den_ += e0;                                                                                 \
    }

__global__ __launch_bounds__(256) void acc_kernel(
    const u16* __restrict__ hb_place, const u16* __restrict__ hb_trans,
    const float* __restrict__ al_place, const float* __restrict__ al_trans,
    const int2* __restrict__ ofp, const int* __restrict__ perm,
    u16* __restrict__ outb)
{
    const int rel = blockIdx.y;
    const u16* hb; const float* als; const float* ald;
    if (rel == 0)      { hb = hb_place; als = al_place + 0 * NN * 4; ald = al_trans + 2 * NN * 4; }
    else if (rel == 1) { hb = hb_trans; als = al_trans + 1 * NN * 4; ald = al_trans + 3 * NN * 4; }
    else if (rel == 2) { hb = hb_trans; als = al_trans + 0 * NN * 4; ald = al_place + 2 * NN * 4; }
    else               { hb = hb_place; als = al_place + 1 * NN * 4; ald = al_place + 3 * NN * 4; }
    const int2* of = ofp + (size_t)rel * NN;
    const int* pm = perm + (size_t)rel * RELSTRIDE;
    u16* ob = outb + (size_t)rel * NN * FO;

    const int lane = threadIdx.x & 63;
    const int wid  = threadIdx.x >> 6;
    const int head = lane >> 4;

    const int gw = blockIdx.x * 4 + wid;
    const int nw = gridDim.x * 4;
    for (int n = gw; n < NN; n += 2 * nw) {
        const int n2 = n + nw;
        const int nu = __builtin_amdgcn_readfirstlane(n);
        const int2 be = of[nu];
        int c1 = be.x;
        const int end1 = be.y;
        const float advh1 = ald[nu * 4 + head];
        float num1 = 0.f, den1 = 0.f;

        if (n2 < NN) {
            const int nu2 = __builtin_amdgcn_readfirstlane(n2);
            const int2 be2 = of[nu2];
            int c2 = be2.x;
            const int end2 = be2.y;
            const float advh2 = ald[nu2 * 4 + head];
            float num2 = 0.f, den2 = 0.f;

            while (c1 + 4 <= end1 && c2 + 4 <= end2) {
                EDGE4(pm, als, hb, c1, advh1, num1, den1, head, lane);
                EDGE4(pm, als, hb, c2, advh2, num2, den2, head, lane);
                c1 += 4; c2 += 4;
            }
            for (; c1 + 4 <= end1; c1 += 4) EDGE4(pm, als, hb, c1, advh1, num1, den1, head, lane);
            for (; c1 < end1; ++c1)         EDGE1(pm, als, hb, c1, advh1, num1, den1, head, lane);
            for (; c2 + 4 <= end2; c2 += 4) EDGE4(pm, als, hb, c2, advh2, num2, den2, head, lane);
            for (; c2 < end2; ++c2)         EDGE1(pm, als, hb, c2, advh2, num2, den2, head, lane);

            const float outv1 = fmaxf(num1 / (den1 + 1e-16f), 0.f);
            const float outv2 = fmaxf(num2 / (den2 + 1e-16f), 0.f);
            ob[(size_t)nu * FO + lane]  = f2bf(outv1);
            ob[(size_t)nu2 * FO + lane] = f2bf(outv2);
        } else {
            for (; c1 + 4 <= end1; c1 += 4) EDGE4(pm, als, hb, c1, advh1, num1, den1, head, lane);
            for (; c1 < end1; ++c1)         EDGE1(pm, als, hb, c1, advh1, num1, den1, head, lane);
            const float outv1 = fmaxf(num1 / (den1 + 1e-16f), 0.f);
            ob[(size_t)nu * FO + lane] = f2bf(outv1);
        }
    }
}

// ---------------- semantic: ts[f] += tanh(out_row @ kW + kb)[f]; 4-row chains ----------------
__global__ __launch_bounds__(256) void sem_kernel(
    const u16* __restrict__ outb, const float* __restrict__ kW, const float* __restrict__ kb,
    float* __restrict__ mean_acc)
{
    const int rel = blockIdx.y;
    const u16* ob = outb + (size_t)rel * NN * FO;
    const int QN = NN / 4;

    const int lane = threadIdx.x & 63;
    const int wid  = threadIdx.x >> 6;

    float kwc[FO];
#pragma unroll
    for (int k = 0; k < FO; ++k) kwc[k] = kW[k * FO + lane];
    const float kbv = kb[lane];

    float ts = 0.f;
    const int gw = blockIdx.x * 4 + wid;
    const int nw = gridDim.x * 4;
    for (int n = gw; n < QN; n += nw) {
        const int r0 = __builtin_amdgcn_readfirstlane(n);
        const int r1 = r0 + QN;
        const int r2 = r0 + 2 * QN;
        const int r3 = r0 + 3 * QN;
        const u32* w0 = (const u32*)(ob + (size_t)r0 * FO);
        const u32* w1 = (const u32*)(ob + (size_t)r1 * FO);
        const u32* w2 = (const u32*)(ob + (size_t)r2 * FO);
        const u32* w3 = (const u32*)(ob + (size_t)r3 * FO);
        float y0 = kbv, y1 = kbv, y2 = kbv, y3 = kbv;
#pragma unroll
        for (int i = 0; i < 32; ++i) {
            const u32 a = w0[i], b = w1[i], c = w2[i], d = w3[i];
            y0 = fmaf(__uint_as_float(a << 16),         kwc[2 * i],     y0);
            y0 = fmaf(__uint_as_float(a & 0xffff0000u), kwc[2 * i + 1], y0);
            y1 = fmaf(__uint_as_float(b << 16),         kwc[2 * i],     y1);
            y1 = fmaf(__uint_as_float(b & 0xffff0000u), kwc[2 * i + 1], y1);
            y2 = fmaf(__uint_as_float(c << 16),         kwc[2 * i],     y2);
            y2 = fmaf(__uint_as_float(c & 0xffff0000u), kwc[2 * i + 1], y2);
            y3 = fmaf(__uint_as_float(d << 16),         kwc[2 * i],     y3);
            y3 = fmaf(__uint_as_float(d & 0xffff0000u), kwc[2 * i + 1], y3);
        }
        ts += (tanhf(y0) + tanhf(y1)) + (tanhf(y2) + tanhf(y3));
    }

    __shared__ float red[4][64];
    red[wid][lane] = ts;
    __syncthreads();
    if (wid == 0) {
        const float sum = red[0][lane] + red[1][lane] + red[2][lane] + red[3][lane];
        unsafeAtomicAdd(&mean_acc[rel * 64 + lane], sum);
    }
}

// ---------------- combine: attn computed inline; out = a0*out_r0 + a1*out_r1 (f32 out) ----------------
__global__ __launch_bounds__(256) void combine_kernel(
    const u16* __restrict__ outb, const float* __restrict__ mean_acc,
    const float* __restrict__ q, float* __restrict__ out)
{
    const int lane = threadIdx.x & 63;
    const int type = blockIdx.y;           // 0 = place (rels 2,3), 1 = trans (rels 0,1)
    const int r0i = (type == 0) ? 2 : 0;

    const float qv = q[lane];
    float s0 = qv * mean_acc[r0i * 64 + lane] * (1.0f / (float)NN);
    float s1 = qv * mean_acc[(r0i + 1) * 64 + lane] * (1.0f / (float)NN);
#pragma unroll
    for (int off = 1; off < 64; off <<= 1) {
        s0 += __shfl_xor(s0, off);
        s1 += __shfl_xor(s1, off);
    }
    const float m = fmaxf(s0, s1);
    const float e0 = expf(s0 - m), e1 = expf(s1 - m);
    const float a0 = e0 / (e0 + e1);
    const float a1 = e1 / (e0 + e1);

    const ushort4* o0 = (const ushort4*)(outb + (size_t)r0i * NN * FO);
    const ushort4* o1 = (const ushort4*)(outb + (size_t)(r0i + 1) * NN * FO);
    float4* dst = (float4*)(out + (size_t)type * NN * FO);
    const int n4 = NN * FO / 4;
    const int stride = gridDim.x * 256;
    for (int i = blockIdx.x * 256 + threadIdx.x; i < n4; i += stride) {
        const ushort4 u = o0[i];
        const ushort4 w = o1[i];
        float4 r;
        r.x = a0 * bf2f(u.x) + a1 * bf2f(w.x);
        r.y = a0 * bf2f(u.y) + a1 * bf2f(w.y);
        r.z = a0 * bf2f(u.z) + a1 * bf2f(w.z);
        r.w = a0 * bf2f(u.w) + a1 * bf2f(w.w);
        dst[i] = r;
    }
}

extern "C" void kernel_launch(void* const* d_in, const int* in_sizes, int n_in,
                              void* d_out, int out_size, void* d_ws, size_t ws_size,
                              hipStream_t stream)
{
    const float* x_place = (const float*)d_in[0];
    const float* x_trans = (const float*)d_in[1];
    const float* W_place = (const float*)d_in[2];
    const float* b_place = (const float*)d_in[3];
    const float* W_trans = (const float*)d_in[4];
    const float* b_trans = (const float*)d_in[5];
    const float* as_pt = (const float*)d_in[6];
    const float* ad_pt = (const float*)d_in[7];
    const float* as_tp = (const float*)d_in[8];
    const float* ad_tp = (const float*)d_in[9];
    const float* as_pp = (const float*)d_in[10];
    const float* ad_pp = (const float*)d_in[11];
    const float* as_tt = (const float*)d_in[12];
    const float* ad_tt = (const float*)d_in[13];
    const float* q  = (const float*)d_in[14];
    const float* kW = (const float*)d_in[15];
    const float* kb = (const float*)d_in[16];
    const int* ei_pt = (const int*)d_in[17];
    const int* ei_tp = (const int*)d_in[18];
    const int* ei_pp = (const int*)d_in[19];
    const int* ei_tt = (const int*)d_in[20];

    // ---- workspace layout ----
    char* ws = (char*)d_ws;
    u16* hb_place = (u16*)ws;                                     // NN*64 bf16 = 12.8 MB
    u16* hb_trans = hb_place + (size_t)NN * FO;                   // 12.8 MB
    float* al_place = (float*)(hb_trans + (size_t)NN * FO);       // 4*NN*4 f32 = 6.4 MB
    float* al_trans = al_place + 4 * (size_t)NN * 4;              // 6.4 MB
    u16* outb = (u16*)(al_trans + 4 * (size_t)NN * 4);            // 4*NN*64 bf16 = 51.2 MB
    int2* ofp = (int2*)(outb + 4 * (size_t)NN * FO);              // 4*NN int2 = 3.2 MB
    int* perm = (int*)(ofp + 4 * (size_t)NN);                     // 4*RELSTRIDE int = 33.6 MB
    u32* packed = (u32*)(perm + 4 * (size_t)RELSTRIDE);           // 4*RELSTRIDE u32 = 33.6 MB
    int* bcursor = (int*)(packed + 4 * (size_t)RELSTRIDE);        // 4*256 int
    float* mean_acc = (float*)(bcursor + 4 * 256);                // 256 f32

    init_kernel<<<4, 256, 0, stream>>>(bcursor, mean_acc);

    phase1_kernel<<<2 * PROJ_T + 4 * PLACE_BLOCKS, 256, 0, stream>>>(
        x_place, W_place, b_place,
        x_trans, W_trans, b_trans,
        hb_place, hb_trans,
        ei_pt, ei_tt, ei_tp, ei_pp, bcursor, packed);

    csr_build_al<<<dim3(NB + ALB, 4), 256, 0, stream>>>(
        packed, bcursor, ofp, perm,
        hb_place, hb_trans,
        as_pt, as_pp, ad_tp, ad_pp,
        as_tp, as_tt, ad_pt, ad_tt,
        al_place, al_trans);

    acc_kernel<<<dim3(1024, 4), 256, 0, stream>>>(hb_place, hb_trans, al_place, al_trans,
                                                  ofp, perm, outb);

    sem_kernel<<<dim3(512, 4), 256, 0, stream>>>(outb, kW, kb, mean_acc);

    combine_kernel<<<dim3(1024, 2), 256, 0, stream>>>(outb, mean_acc, q, (float*)d_out);
}